// Round 1
// baseline (40.023 us; speedup 1.0000x reference)
//
#include <hip/hip_runtime.h>

// GatherRouter: top-2 MoE combine.
// tags[p] is a permutation of [0,T) -> out[t] = data[0][inv0[t]] + data[1][inv1[t]].

__global__ void build_inverse_kernel(const int* __restrict__ tags,
                                     int* __restrict__ inv,
                                     int T, int N) {
    int i = blockIdx.x * blockDim.x + threadIdx.x;
    if (i < N) {
        int p = i / T;          // flow index
        int pos = i - p * T;    // position within flow
        int t = tags[i];        // tag value in [0, T)
        inv[p * T + t] = pos;   // inverse permutation
    }
}

// One block per output row. D4 = D/4 float4 elements per row.
__global__ void gather_add_kernel(const float4* __restrict__ data,
                                  const int* __restrict__ inv,
                                  float4* __restrict__ out,
                                  int T, int D4) {
    int row = blockIdx.x;
    int i0 = inv[row];          // source row in flow 0
    int i1 = inv[T + row];      // source row in flow 1
    const float4* a = data + (size_t)i0 * D4;
    const float4* b = data + ((size_t)T + (size_t)i1) * D4;
    float4* o = out + (size_t)row * D4;
    for (int c = threadIdx.x; c < D4; c += blockDim.x) {
        float4 va = a[c];
        float4 vb = b[c];
        float4 v;
        v.x = va.x + vb.x;
        v.y = va.y + vb.y;
        v.z = va.z + vb.z;
        v.w = va.w + vb.w;
        o[c] = v;
    }
}

extern "C" void kernel_launch(void* const* d_in, const int* in_sizes, int n_in,
                              void* d_out, int out_size, void* d_ws, size_t ws_size,
                              hipStream_t stream) {
    const float* data = (const float*)d_in[0];   // [P, T, D] f32
    const int* tags   = (const int*)d_in[1];     // [P, T] (int64 in ref, int32 here)
    // d_in[2] = load (scalar) — not needed; derive shapes from sizes.

    const int N  = in_sizes[1];          // P*T = 16384
    const int D  = in_sizes[0] / N;      // 2048
    const int T  = out_size / D;         // 8192
    const int D4 = D / 4;                // 512

    int* inv = (int*)d_ws;               // P*T ints = 64 KB scratch

    // Pass 1: inverse permutations.
    build_inverse_kernel<<<(N + 255) / 256, 256, 0, stream>>>(tags, inv, T, N);

    // Pass 2: gather + add, one block per output row.
    gather_add_kernel<<<T, 256, 0, stream>>>((const float4*)data, inv,
                                             (float4*)d_out, T, D4);
}